// Round 11
// baseline (284.553 us; speedup 1.0000x reference)
//
#include <hip/hip_runtime.h>
#include <hip/hip_bf16.h>

#define NN 1024
#define IN_CH 128
#define EDGE_CH 32
#define OUT_CH 128
#define NNSQ ((size_t)NN * (size_t)NN)

typedef __attribute__((ext_vector_type(8))) short bf16x8;
typedef __attribute__((ext_vector_type(4))) float f32x4;

// round-to-nearest-even float -> bf16 (bit trick)
static __device__ __forceinline__ short f2bf(float f) {
    union { float f; unsigned u; } v; v.f = f;
    unsigned r = v.u + 0x7FFFu + ((v.u >> 16) & 1u);
    return (short)(r >> 16);
}

// ---------------------------------------------------------------------------
// Kernel A: P = node_mat @ node_weight (stored TRANSPOSED, bf16: PT[o][m]),
//           R = node_mat @ root (fp32).  (unchanged)
// ---------------------------------------------------------------------------
__global__ void node_gemm_kernel(const float* __restrict__ node_mat,
                                 const float* __restrict__ node_weight,
                                 const float* __restrict__ root,
                                 short* __restrict__ PT,
                                 float* __restrict__ R) {
    __shared__ float nm[2 * IN_CH];
    int tid = threadIdx.x;
    int n0 = blockIdx.x * 2;
    nm[tid] = node_mat[n0 * IN_CH + tid];
    __syncthreads();
    int o = tid & 127;
    int h = tid >> 7;
    const float* nr = &nm[h * IN_CH];
    float accp = 0.f, accr = 0.f;
#pragma unroll 8
    for (int c = 0; c < IN_CH; ++c) {
        float x = nr[c];
        accp += x * node_weight[c * OUT_CH + o];
        accr += x * root[c * OUT_CH + o];
    }
    R[(size_t)(n0 + h) * OUT_CH + o] = accr;
    PT[(size_t)o * NN + (n0 + h)] = f2bf(accp);  // transposed bf16 store
}

// ---------------------------------------------------------------------------
// Kernel C (runs before edge_out): out = adj @ P + R + bias  (WRITE mode).
// (unchanged)
// ---------------------------------------------------------------------------
__global__ void adjp_kernel(const float* __restrict__ adj,
                            const short* __restrict__ PT,
                            const float* __restrict__ R,
                            const float* __restrict__ bias,
                            float* __restrict__ out) {
    int blk = blockIdx.x;
    int nb = blk & 63;          // n-tile: 16 rows
    int oh = blk >> 6;          // o-half: 64 cols
    int tid = threadIdx.x;
    int wave = tid >> 6;
    int lane = tid & 63;
    int quad = lane >> 4;
    int col  = lane & 15;
    int n0 = nb * 16;
    int o0 = oh * 64;

    f32x4 acc[4];
#pragma unroll
    for (int ot = 0; ot < 4; ++ot) acc[ot] = (f32x4){0.f, 0.f, 0.f, 0.f};

    int kbase = wave * 256;     // wave-level K-split, reduced in LDS below
#pragma unroll
    for (int ks = 0; ks < 8; ++ks) {
        int k = kbase + ks * 32 + quad * 8;
        const float* ap = adj + (size_t)(n0 + col) * NN + k;
        f32x4 a0 = *(const f32x4*)ap;
        f32x4 a1 = *(const f32x4*)(ap + 4);
        bf16x8 a;
#pragma unroll
        for (int j = 0; j < 4; ++j) { a[j] = f2bf(a0[j]); a[4 + j] = f2bf(a1[j]); }
#pragma unroll
        for (int ot = 0; ot < 4; ++ot) {
            int o = o0 + ot * 16 + col;
            bf16x8 b = *(const bf16x8*)(PT + (size_t)o * NN + k);
            acc[ot] = __builtin_amdgcn_mfma_f32_16x16x32_bf16(a, b, acc[ot], 0, 0, 0);
        }
    }

    __shared__ float red[4][16][65];
#pragma unroll
    for (int ot = 0; ot < 4; ++ot)
#pragma unroll
        for (int r = 0; r < 4; ++r)
            red[wave][quad * 4 + r][ot * 16 + col] = acc[ot][r];
    __syncthreads();

#pragma unroll
    for (int i = tid; i < 16 * 64; i += 256) {
        int rr = i >> 6;
        int cc = i & 63;
        float v = red[0][rr][cc] + red[1][rr][cc] + red[2][rr][cc] + red[3][rr][cc];
        size_t idx = (size_t)(n0 + rr) * OUT_CH + o0 + cc;
        out[idx] = v + R[idx] + bias[o0 + cc];
    }
}

// ---------------------------------------------------------------------------
// Kernel B v10 (heavy): per node n,
//   G[b]  = sum_m adj[n,m] * relu( sum_e edge_adj[e,n,m] * L1[e,b] )
//   out[n,o] += sum_{b<127} G[b]*L2[b,o]            (base pre-written by adjp)
//
// v9 post-mortem: breadth (5 blocks/CU) null -> in-flight bytes are NOT the
// limiter. Six source-level knobs leave the 32-stream 4-MiB-stride gather at
// ~1.9 TB/s with all pipes idle. The ONE untried structural path:
// __builtin_amdgcn_global_load_lds (direct HBM->LDS, no VGPR return, no
// staging registers -> spill-proof; the m93->m97 +69% primitive).
//   - chunk = 256 m x 32 e f32, staged as 32 linear 1-KB planes, one
//     gload_lds dwordx4 per plane (wave w issues planes 8w..8w+7).
//   - PRE-ROTATED source (pre-swizzle pattern): plane p staged with m
//     rotated by 8*(p>>3); read index (mloc - 8*quad) & 255 -> the frag
//     ds_read_b32 gathers are 2-way-per-bank = conflict-free. (Padding is
//     impossible: gload_lds needs 16B-aligned linear planes.)
//   - double-buffer = 64 KB exactly; adj values live in 16 regs/lane;
//     epilogue arrays alias the staging LDS after a barrier.
//   - schedule per chunk: STAGE(next) -> COMPUTE(cur) -> __syncthreads()
//     (the barrier's vmcnt(0) is the drain; loads fly during compute).
//   - compute: v2-proven wave-m-split (wave owns 64 m/chunk: 4 subtiles x
//     8 b-tiles, g_acc[8][4]) + shuffle/gred/epilogue.
// MFMA 16x16x32: A=L1^T const frags [b][e]; B-frag assembled from LDS
// (8 x ds_read_b32 + f2bf pack); D row=quad*4+r (b), col=m.
// ---------------------------------------------------------------------------
__global__ void __launch_bounds__(256, 2)
edge_out_kernel(const float* __restrict__ edge_adj,
                const float* __restrict__ adj,
                const float* __restrict__ L1,
                const float* __restrict__ L2,
                float* __restrict__ out) {
    int n = blockIdx.x;
    int tid = threadIdx.x;
    int wave = tid >> 6;
    int lane = tid & 63;
    int quad = lane >> 4;
    int col  = lane & 15;

    // 2 x (32 planes x 256 f32) = 64 KB exactly (epilogue aliases into this)
    __shared__ __attribute__((aligned(16))) float ea_lds[2][32 * 256];

    // A fragments: 8 b-tiles of L1^T [b=bt*16+col][e=quad*8+j]
    bf16x8 a_frag[8];
#pragma unroll
    for (int bt = 0; bt < 8; ++bt) {
        int b = bt * 16 + col;
#pragma unroll
        for (int j = 0; j < 8; ++j) {
            int e = quad * 8 + j;
            float v = (b < OUT_CH - 1) ? L1[e * (OUT_CH - 1) + b] : 0.0f;  // pad b=127
            a_frag[bt][j] = f2bf(v);
        }
    }

    float g_acc[8][4];
#pragma unroll
    for (int bt = 0; bt < 8; ++bt)
#pragma unroll
        for (int r = 0; r < 4; ++r) g_acc[bt][r] = 0.0f;

    // adj values in registers: adjv[chunk][subtile], m = CR(c)*256 + wave*64 + s*16 + col
    const int cr0 = n & 3, cr1 = (n + 1) & 3, cr2 = (n + 2) & 3, cr3 = (n + 3) & 3;
    float adjv[4][4];
    {
        const float* ar = adj + (size_t)n * NN + wave * 64 + col;
#pragma unroll
        for (int s = 0; s < 4; ++s) {
            adjv[0][s] = ar[cr0 * 256 + s * 16];
            adjv[1][s] = ar[cr1 * 256 + s * 16];
            adjv[2][s] = ar[cr2 * 256 + s * 16];
            adjv[3][s] = ar[cr3 * 256 + s * 16];
        }
    }

    // staging: wave w issues its 8 planes, lane covers 4 m (rotated by 8*wave)
    int rot = wave * 8;
    int moff = (lane * 4 + rot) & 255;               // never splits a 4-float group
    const float* ea_base = edge_adj + (size_t)(wave * 8) * NNSQ + (size_t)n * NN + moff;

#define STAGE(BUFIDX, AC) { \
        const float* g_ = ea_base + (AC) * 256; \
        float* l_ = &ea_lds[BUFIDX][wave * 8 * 256]; \
        _Pragma("unroll") for (int j = 0; j < 8; ++j) { \
            __builtin_amdgcn_global_load_lds( \
                (const __attribute__((address_space(1))) unsigned*)(g_ + j * NNSQ), \
                (__attribute__((address_space(3))) unsigned*)(l_ + j * 256), \
                16, 0, 0); } }
#define COMPUTE(BUFIDX, CI) { \
        _Pragma("unroll") for (int s = 0; s < 4; ++s) { \
            int mloc = wave * 64 + s * 16 + col; \
            int d = (mloc - quad * 8) & 255;         /* un-rotate for this quad */ \
            const float* bp = &ea_lds[BUFIDX][quad * 8 * 256 + d]; \
            bf16x8 bfv; \
            _Pragma("unroll") for (int j = 0; j < 8; ++j) \
                bfv[j] = f2bf(bp[j * 256]); \
            float av = adjv[CI][s]; \
            _Pragma("unroll") for (int bt = 0; bt < 8; ++bt) { \
                f32x4 dd = __builtin_amdgcn_mfma_f32_16x16x32_bf16( \
                    a_frag[bt], bfv, (f32x4){0.f, 0.f, 0.f, 0.f}, 0, 0, 0); \
                _Pragma("unroll") for (int r = 0; r < 4; ++r) \
                    g_acc[bt][r] += fmaxf(dd[r], 0.0f) * av; } } }

    // STAGE(next) -> COMPUTE(cur) -> barrier (barrier's vmcnt(0) drains loads)
    STAGE(0, cr0);
    __syncthreads();
    STAGE(1, cr1); COMPUTE(0, 0); __syncthreads();
    STAGE(0, cr2); COMPUTE(1, 1); __syncthreads();
    STAGE(1, cr3); COMPUTE(0, 2); __syncthreads();
    COMPUTE(1, 3);
    __syncthreads();                 // before aliasing ea_lds for the epilogue

#undef STAGE
#undef COMPUTE

    // reduce over the 16 column-lanes (sum over m within subtile columns)
#pragma unroll
    for (int bt = 0; bt < 8; ++bt)
#pragma unroll
        for (int r = 0; r < 4; ++r) {
            float v = g_acc[bt][r];
            v += __shfl_xor(v, 1);
            v += __shfl_xor(v, 2);
            v += __shfl_xor(v, 4);
            v += __shfl_xor(v, 8);
            g_acc[bt][r] = v;
        }

    // epilogue scratch aliases the (now-dead) staging buffer
    float* gred = &ea_lds[0][0];          // [4][128]
    float* gs   = gred + 4 * OUT_CH;      // [128]
    float* part = gs + OUT_CH;            // [2][128]

    if (col == 0) {
#pragma unroll
        for (int bt = 0; bt < 8; ++bt)
#pragma unroll
            for (int r = 0; r < 4; ++r)
                gred[wave * OUT_CH + bt * 16 + quad * 4 + r] = g_acc[bt][r];
    }
    __syncthreads();
    if (tid < OUT_CH)
        gs[tid] = gred[0 * OUT_CH + tid] + gred[1 * OUT_CH + tid] +
                  gred[2 * OUT_CH + tid] + gred[3 * OUT_CH + tid];
    __syncthreads();

    // epilogue: out[n,o] += sum_{b<127} gs[b]*L2[b,o]   (plain rmw, single writer)
    int o = tid & 127;
    int hf = tid >> 7;
    float acc = 0.f;
    int blo = hf * 64, bhi = hf ? 127 : 64;
#pragma unroll 8
    for (int b = blo; b < bhi; ++b)
        acc += gs[b] * L2[b * OUT_CH + o];   // gs[b] is an LDS broadcast (free)
    part[hf * OUT_CH + o] = acc;
    __syncthreads();
    if (tid < 128) {
        size_t idx = (size_t)n * OUT_CH + tid;
        out[idx] += part[0 * OUT_CH + tid] + part[1 * OUT_CH + tid];
    }
}

extern "C" void kernel_launch(void* const* d_in, const int* in_sizes, int n_in,
                              void* d_out, int out_size, void* d_ws, size_t ws_size,
                              hipStream_t stream) {
    const float* node_mat    = (const float*)d_in[0];
    const float* adj         = (const float*)d_in[1];
    const float* edge_adj    = (const float*)d_in[2];
    const float* node_weight = (const float*)d_in[3];
    const float* edge_lay_1  = (const float*)d_in[4];
    const float* edge_lay_2  = (const float*)d_in[5];
    const float* root        = (const float*)d_in[6];
    const float* bias        = (const float*)d_in[7];
    float* out = (float*)d_out;

    short* PT = (short*)d_ws;                       // 128*1024 bf16 = 256 KB
    float* R  = (float*)((char*)d_ws + OUT_CH * NN * sizeof(short));  // 512 KB

    node_gemm_kernel<<<NN / 2, 256, 0, stream>>>(node_mat, node_weight, root, PT, R);
    adjp_kernel<<<128, 256, 0, stream>>>(adj, PT, R, bias, out);   // writes base
    edge_out_kernel<<<NN, 256, 0, stream>>>(edge_adj, adj, edge_lay_1,
                                            edge_lay_2, out);      // plain +=
}